// Round 4
// baseline (413.137 us; speedup 1.0000x reference)
//
#include <hip/hip_runtime.h>
#include <hip/hip_bf16.h>

typedef unsigned short u16;
typedef unsigned int u32;
typedef __attribute__((ext_vector_type(8))) short short8;
typedef __attribute__((ext_vector_type(4))) short short4v;
typedef __attribute__((ext_vector_type(4))) float floatx4;

__device__ __forceinline__ float bf2f(u16 u) {
    union { u32 u; float f; } x; x.u = ((u32)u) << 16; return x.f;
}
__device__ __forceinline__ u16 f2bf(float f) {
    union { float f; u32 u; } x; x.f = f;
    u32 r = x.u + 0x7FFFu + ((x.u >> 16) & 1u);
    return (u16)(r >> 16);
}

// ---------------------------------------------------------------------------
// Convert the 8 big fp32 tensors to canonical bf16 buffers in ws.
// All segment sizes are multiples of 4 -> operate on float4 groups.
// ---------------------------------------------------------------------------
struct Cvt8 {
    const float* src[8];
    u16* dst[8];
    int pre[9];   // prefix sums in float4-groups
};

__global__ __launch_bounds__(256) void convert8(Cvt8 a) {
    int total = a.pre[8];
    for (int g = blockIdx.x * 256 + threadIdx.x; g < total; g += gridDim.x * 256) {
        int seg = 0;
        while (a.pre[seg + 1] <= g) seg++;
        int off = g - a.pre[seg];
        float4 f = ((const float4*)a.src[seg])[off];
        short4v o;
        o[0] = (short)f2bf(f.x); o[1] = (short)f2bf(f.y);
        o[2] = (short)f2bf(f.z); o[3] = (short)f2bf(f.w);
        *(short4v*)(a.dst[seg] + (long)off * 4) = o;
    }
}

// ---------------------------------------------------------------------------
// Fold the (affine) relative-position MLP (fp32 in, fp32 out):
// Weff[d][p] = sum_e w2[d][e]*w1[e][p];  beff[d] = sum_e w2[d][e]*b1[e]+b2[d]
// Stored padded [64][8]: cols 0..3 = Weff, col 4 = beff.
// ---------------------------------------------------------------------------
__global__ void prep_w5(const float* __restrict__ w1, const float* __restrict__ b1,
                        const float* __restrict__ w2, const float* __restrict__ b2,
                        float* __restrict__ W5) {
    int d = threadIdx.x;  // 64 threads
    float a0=0.f,a1=0.f,a2=0.f,a3=0.f,ab=0.f;
    for (int e=0;e<64;++e) {
        float w = w2[d*64+e];
        a0 = fmaf(w, w1[e*4+0], a0);
        a1 = fmaf(w, w1[e*4+1], a1);
        a2 = fmaf(w, w1[e*4+2], a2);
        a3 = fmaf(w, w1[e*4+3], a3);
        ab = fmaf(w, b1[e], ab);
    }
    W5[d*8+0]=a0; W5[d*8+1]=a1; W5[d*8+2]=a2; W5[d*8+3]=a3;
    W5[d*8+4]=ab + b2[d];
    W5[d*8+5]=0.f; W5[d*8+6]=0.f; W5[d*8+7]=0.f;
}

// ---------------------------------------------------------------------------
// MFMA bf16 GEMM: C[m,n] = sum_k A[m,k]*B[n,k]  (both row-major [rows,K]).
// MODE_AV stages A from fp32 (attn lives in d_out as fp32).
// ---------------------------------------------------------------------------
enum { MODE_QK=0, MODE_VT=1, MODE_AV=2, MODE_FC=3, MODE_FFN1=4, MODE_FFN2=5 };

template<int MODE>
__global__ __launch_bounds__(256,2)
void mfma_gemm(const u16* __restrict__ A, const float* __restrict__ Af, long sA,
               const u16* __restrict__ B, long sB,
               const float* __restrict__ biasf,
               const float* __restrict__ resf,
               void* __restrict__ outp,
               int M, int N, int K)
{
    int bz = blockIdx.z;
    const u16* Bb = B + (long)bz * sB;
    int m0 = blockIdx.x * 64, n0 = blockIdx.y * 64;
    __shared__ __align__(16) u16 As[64*40];   // row stride 40 (pad 8)
    __shared__ __align__(16) u16 Bs[64*40];
    int tid = threadIdx.x;
    int lane = tid & 63, wave = tid >> 6;
    int wm = (wave >> 1) * 32, wn = (wave & 1) * 32;
    int mrow = lane & 15, quad = lane >> 4;
    floatx4 zz = {0.f,0.f,0.f,0.f};
    floatx4 acc[2][2];
    acc[0][0]=zz; acc[0][1]=zz; acc[1][0]=zz; acc[1][1]=zz;
    int r = tid >> 2, cc = (tid & 3) * 8;
    const u16*   pa  = A  + (long)bz * sA + (long)(m0 + r) * K + cc;
    const float* paf = Af + (long)bz * sA + (long)(m0 + r) * K + cc;
    const u16* pb = Bb + (long)(n0 + r) * K + cc;
    u16* asp = &As[r*40 + cc];
    u16* bsp = &Bs[r*40 + cc];
    const u16* a0p = &As[(wm + mrow)*40];
    const u16* a1p = &As[(wm + 16 + mrow)*40];
    const u16* b0p = &Bs[(wn + mrow)*40];
    const u16* b1p = &Bs[(wn + 16 + mrow)*40];
    int qo = quad * 8;
    for (int k0 = 0; k0 < K; k0 += 32) {
        if constexpr (MODE == MODE_AV) {
            floatx4 f0 = *(const floatx4*)(paf + k0);
            floatx4 f1 = *(const floatx4*)(paf + k0 + 4);
            short4v t0, t1;
            #pragma unroll
            for (int e=0;e<4;++e) { t0[e] = (short)f2bf(f0[e]); t1[e] = (short)f2bf(f1[e]); }
            *(short4v*)asp       = t0;
            *(short4v*)(asp + 4) = t1;
        } else {
            *(short8*)asp = *(const short8*)(pa + k0);
        }
        *(short8*)bsp = *(const short8*)(pb + k0);
        __syncthreads();
        short8 af0 = *(const short8*)(a0p + qo);
        short8 af1 = *(const short8*)(a1p + qo);
        short8 bf0 = *(const short8*)(b0p + qo);
        short8 bf1 = *(const short8*)(b1p + qo);
        acc[0][0] = __builtin_amdgcn_mfma_f32_16x16x32_bf16(af0, bf0, acc[0][0], 0,0,0);
        acc[0][1] = __builtin_amdgcn_mfma_f32_16x16x32_bf16(af0, bf1, acc[0][1], 0,0,0);
        acc[1][0] = __builtin_amdgcn_mfma_f32_16x16x32_bf16(af1, bf0, acc[1][0], 0,0,0);
        acc[1][1] = __builtin_amdgcn_mfma_f32_16x16x32_bf16(af1, bf1, acc[1][1], 0,0,0);
        __syncthreads();
    }
    if constexpr (MODE == MODE_VT) {
        // store C^T (vt[(b,h)][d][i]) via LDS transpose
        __shared__ __align__(16) float Cs[64][65];
        #pragma unroll
        for (int im=0; im<2; ++im)
        #pragma unroll
        for (int in=0; in<2; ++in)
        #pragma unroll
        for (int rr=0; rr<4; ++rr)
            Cs[wm + im*16 + quad*4 + rr][wn + in*16 + mrow] = acc[im][in][rr];
        __syncthreads();
        u16* vt = (u16*)outp;
        int b = m0 >> 9, i0b = m0 & 511, hh = n0 >> 6;
        #pragma unroll
        for (int t=0;t<16;++t) {
            int flat = tid + t*256;
            int d = flat >> 6, il = flat & 63;
            vt[(((long)(b*8 + hh)*64 + d) << 9) + i0b + il] = f2bf(Cs[il][d]);
        }
    } else {
        #pragma unroll
        for (int im=0; im<2; ++im)
        #pragma unroll
        for (int in=0; in<2; ++in)
        #pragma unroll
        for (int rr=0; rr<4; ++rr) {
            int mm = m0 + wm + im*16 + quad*4 + rr;
            int nn = n0 + wn + in*16 + mrow;
            float v = acc[im][in][rr];
            if constexpr (MODE == MODE_QK) {
                // store [b,h,i,d] from row=(b,i), col=(h,d)
                int b = mm >> 9, i = mm & 511, hh = nn >> 6, d = nn & 63;
                ((u16*)outp)[(((long)(b*8 + hh) * 512 + i) << 6) + d] = f2bf(v);
            } else if constexpr (MODE == MODE_AV) {
                // batched (b,h); out[b, j, h*64+d]
                int b = bz >> 3, hh = bz & 7;
                ((u16*)outp)[((long)(b*512 + mm)) * 512 + hh*64 + nn] = f2bf(v);
            } else if constexpr (MODE == MODE_FC) {
                ((float*)outp)[(long)mm*512 + nn] = v + resf[(long)mm*512 + nn];
            } else if constexpr (MODE == MODE_FFN1) {
                float t = v + biasf[nn];
                ((u16*)outp)[(long)mm*2048 + nn] = f2bf(t > 0.f ? t : 0.f);
            } else { // MODE_FFN2
                ((float*)outp)[(long)mm*512 + nn] =
                    v + biasf[nn] + resf[(long)mm*512 + nn];
            }
        }
    }
}

// ---------------------------------------------------------------------------
// Scores + softmax:
// s[b,h,j,i] = (1/8) * sum_d q[b,h,i,d]*k[b,h,j,d]*(pos[b,j,i,:]·Weff[d,:]+beff[d])
// Block = (j-tile 16, h, b); full i-row (512) in LDS -> in-block softmax.
// Writes attn fp32 directly to d_out (output 1, at float offset 1048576).
// ---------------------------------------------------------------------------
__global__ __launch_bounds__(256,2)
void attn_scores(const u16* __restrict__ qws, const u16* __restrict__ kws,
                 const u16* __restrict__ pos, const float* __restrict__ W5g,
                 float* __restrict__ attn_of)
{
    int jt = blockIdx.x, h = blockIdx.y, b = blockIdx.z;
    int j0 = jt * 16;
    int bh = b*8 + h;
    const u16* qb = qws + (long)bh * 512 * 64;
    const u16* kb = kws + ((long)bh * 512 + (long)j0) * 64;
    __shared__ __align__(16) float Qs[64][64];   // [d][i_local] 16 KB
    __shared__ __align__(16) float Ks[64][16];   // [d][j_local]  4 KB
    __shared__ __align__(16) float W5s[64*8];    //               2 KB
    __shared__ __align__(16) float S[16][512];   //              32 KB
    __shared__ __align__(16) float redm[16][17];
    __shared__ __align__(16) float reds[16][17];
    __shared__ float rinvs[16];
    int tid = threadIdx.x;
    if (tid < 64) {
        #pragma unroll
        for (int p=0;p<8;++p) W5s[tid*8+p] = W5g[tid*8+p];
    }
    if (tid < 128) {
        int jl = tid >> 3, dbase = (tid & 7) * 8;
        short8 kv8 = *(const short8*)(kb + jl*64 + dbase);
        #pragma unroll
        for (int e=0;e<8;++e) Ks[dbase+e][jl] = bf2f((u16)kv8[e]);
    }
    int tj = tid >> 4, ti = tid & 15;   // 16 j-threads x 16 i-groups
    int jg = j0 + tj;
    for (int ic=0; ic<8; ++ic) {
        int i0 = ic * 64;
        __syncthreads();
        {   // stage Q^T chunk: Qs[d][il], 64 i-rows, 4 threads/row
            int il = tid >> 2, dbase = (tid & 3) * 16;
            const u16* qq = qb + (long)(i0 + il) * 64 + dbase;
            short8 qa  = *(const short8*)(qq);
            short8 qbv = *(const short8*)(qq + 8);
            #pragma unroll
            for (int e=0;e<8;++e) Qs[dbase+e][il]   = bf2f((u16)qa[e]);
            #pragma unroll
            for (int e=0;e<8;++e) Qs[dbase+8+e][il] = bf2f((u16)qbv[e]);
        }
        __syncthreads();
        float pv[4][4];
        #pragma unroll
        for (int ii=0;ii<4;++ii) {
            int i = i0 + ti*4 + ii;
            uint2 pp = *(const uint2*)&pos[(((long)(b*512 + jg))*512 + i)*4];
            pv[ii][0] = bf2f((u16)(pp.x & 0xffff));
            pv[ii][1] = bf2f((u16)(pp.x >> 16));
            pv[ii][2] = bf2f((u16)(pp.y & 0xffff));
            pv[ii][3] = bf2f((u16)(pp.y >> 16));
        }
        float s[4] = {0.f,0.f,0.f,0.f};
        for (int d=0; d<64; ++d) {
            floatx4 qv = *(const floatx4*)&Qs[d][ti*4];
            floatx4 wv = *(const floatx4*)&W5s[d*8];
            float w4 = W5s[d*8+4];
            float kj = Ks[d][tj];
            #pragma unroll
            for (int ii=0;ii<4;++ii) {
                float ak = fmaf(pv[ii][0], wv[0], w4);
                ak = fmaf(pv[ii][1], wv[1], ak);
                ak = fmaf(pv[ii][2], wv[2], ak);
                ak = fmaf(pv[ii][3], wv[3], ak);
                s[ii] = fmaf(qv[ii]*kj, ak, s[ii]);
            }
        }
        floatx4 sv = { s[0]*0.125f, s[1]*0.125f, s[2]*0.125f, s[3]*0.125f };
        *(floatx4*)&S[tj][i0 + ti*4] = sv;
    }
    __syncthreads();
    // softmax over i (axis=-1): 16 threads per j-row
    int j = tid >> 4, sub = tid & 15;
    float mx = -1e30f;
    for (int t=0;t<32;++t) mx = fmaxf(mx, S[j][sub + t*16]);
    redm[j][sub] = mx;
    __syncthreads();
    float m = redm[j][0];
    #pragma unroll
    for (int p=1;p<16;++p) m = fmaxf(m, redm[j][p]);
    float sum = 0.f;
    for (int t=0;t<32;++t) {
        int i = sub + t*16;
        float e = __expf(S[j][i] - m);
        S[j][i] = e;
        sum += e;
    }
    reds[j][sub] = sum;
    __syncthreads();
    float tot = 0.f;
    #pragma unroll
    for (int p=0;p<16;++p) tot += reds[j][p];
    if (sub == 0) rinvs[j] = 1.0f / tot;
    __syncthreads();
    long rowbase = ((long)bh * 512 + j0) * 512;
    for (int t=0;t<16;++t) {
        int idx = (tid + t*256) * 2;
        int jj = idx >> 9, i = idx & 511;
        float ri = rinvs[jj];
        float2 f2; f2.x = S[jj][i]*ri; f2.y = S[jj][i+1]*ri;
        *(float2*)&attn_of[rowbase + (long)jj*512 + i] = f2;
    }
}

// ---------------------------------------------------------------------------
// LayerNorm over 512 cols, fp32 in; writes bf16 (outb) and/or fp32 (outf).
// ---------------------------------------------------------------------------
__global__ __launch_bounds__(256)
void ln_kernel(const float* __restrict__ x, const float* __restrict__ g,
               const float* __restrict__ bb, u16* __restrict__ outb,
               float* __restrict__ outf)
{
    int row = blockIdx.x, tid = threadIdx.x;
    const float* xr = x + (long)row * 512;
    float v0 = xr[tid*2], v1 = xr[tid*2+1];
    __shared__ float r1[256], r2[256];
    r1[tid] = v0 + v1;
    r2[tid] = v0*v0 + v1*v1;
    __syncthreads();
    for (int sft=128; sft>0; sft>>=1) {
        if (tid < sft) { r1[tid] += r1[tid+sft]; r2[tid] += r2[tid+sft]; }
        __syncthreads();
    }
    float mu = r1[0] * (1.0f/512.0f);
    float var = r2[0] * (1.0f/512.0f) - mu*mu;
    float rs = rsqrtf(var + 1e-6f);
    float y0 = fmaf((v0-mu)*rs, g[tid*2],   bb[tid*2]);
    float y1 = fmaf((v1-mu)*rs, g[tid*2+1], bb[tid*2+1]);
    if (outf) {
        float2 f2; f2.x = y0; f2.y = y1;
        *(float2*)&outf[(long)row*512 + tid*2] = f2;
    }
    if (outb) {
        ((u32*)outb)[row*256 + tid] = (u32)f2bf(y0) | ((u32)f2bf(y1) << 16);
    }
}

// ---------------------------------------------------------------------------
// ws layout (MB), peak 22.13:
//   0-2    enc_c (bf16)                       [live: proj phase]
//   2-10   pos_c (bf16)        -> res12/res2 fp32 (2-6) + ln1f fp32 (6-10)
//   10-12  wq,wk,wv,wfc canon (0.5 each)      [live: whole run]
//   12-14  fw1_c; 14-16 fw2_c                 [live: whole run]
//   16-18  qws  -> aows
//   18-20  kws  -> ln1ws (bf16)
//   20-22  vtws -> hchunk (512x2048 bf16)
//   22-22.13 W5
// ---------------------------------------------------------------------------
extern "C" void kernel_launch(void* const* d_in, const int* in_sizes, int n_in,
                              void* d_out, int out_size, void* d_ws, size_t ws_size,
                              hipStream_t stream)
{
    const float* enc_f  = (const float*)d_in[0];
    const float* pos_f  = (const float*)d_in[1];
    const float* rp_w1  = (const float*)d_in[6];
    const float* rp_b1  = (const float*)d_in[7];
    const float* rp_w2  = (const float*)d_in[8];
    const float* rp_b2  = (const float*)d_in[9];
    const float* ln1_g  = (const float*)d_in[10];
    const float* ln1_b  = (const float*)d_in[11];
    const float* ln2_g  = (const float*)d_in[12];
    const float* ln2_b  = (const float*)d_in[13];
    const float* ffn_b1 = (const float*)d_in[15];
    const float* ffn_b2 = (const float*)d_in[17];

    char* ws = (char*)d_ws;
    const size_t MB = 1048576ul;
    u16* enc_c = (u16*)(ws + 0);
    u16* pos_c = (u16*)(ws + 2*MB);
    u16* wq_c  = (u16*)(ws + 10*MB);
    u16* wk_c  = (u16*)(ws + 10*MB + 524288);
    u16* wv_c  = (u16*)(ws + 11*MB);
    u16* wfc_c = (u16*)(ws + 11*MB + 524288);
    u16* fw1_c = (u16*)(ws + 12*MB);
    u16* fw2_c = (u16*)(ws + 14*MB);
    u16*   qws    = (u16*)(ws + 16*MB);
    u16*   kws    = (u16*)(ws + 18*MB);
    u16*   vtws   = (u16*)(ws + 20*MB);
    float* res12  = (float*)(ws + 2*MB);     // alias pos_c (dead after attn)
    float* ln1f   = (float*)(ws + 6*MB);     // alias pos_c (dead after attn)
    u16*   aows   = (u16*)(ws + 16*MB);      // alias qws (dead after attn)
    u16*   ln1ws  = (u16*)(ws + 18*MB);      // alias kws (dead after attn)
    u16*   hchunk = (u16*)(ws + 20*MB);      // alias vtws (dead after AV)
    float* W5     = (float*)(ws + 22*MB);

    float* out0_f = (float*)d_out;               // output 0: [4,512,512] fp32
    float* attn_f = out0_f + 1048576;            // output 1: [4,8,512,512] fp32

    dim3 blk(256);

    // fp32 -> bf16 canonicalization of the 8 big tensors
    Cvt8 ca;
    const float* srcs[8] = { enc_f, pos_f, (const float*)d_in[2],
                             (const float*)d_in[3], (const float*)d_in[4],
                             (const float*)d_in[5], (const float*)d_in[14],
                             (const float*)d_in[16] };
    u16* dsts[8] = { enc_c, pos_c, wq_c, wk_c, wv_c, wfc_c, fw1_c, fw2_c };
    int sizes4[8] = { 262144, 1048576, 65536, 65536, 65536, 65536, 262144, 262144 };
    int pre = 0;
    for (int i = 0; i < 8; ++i) {
        ca.src[i] = srcs[i]; ca.dst[i] = dsts[i]; ca.pre[i] = pre;
        pre += sizes4[i];
    }
    ca.pre[8] = pre;
    convert8<<<dim3(8192), blk, 0, stream>>>(ca);

    prep_w5<<<dim3(1), dim3(64), 0, stream>>>(rp_w1, rp_b1, rp_w2, rp_b2, W5);

    // Q, K, V^T projections (bf16 MFMA)
    mfma_gemm<MODE_QK><<<dim3(32,8,1), blk, 0, stream>>>(
        enc_c, nullptr, 0L, wq_c, 0L, nullptr, nullptr, (void*)qws, 2048, 512, 512);
    mfma_gemm<MODE_QK><<<dim3(32,8,1), blk, 0, stream>>>(
        enc_c, nullptr, 0L, wk_c, 0L, nullptr, nullptr, (void*)kws, 2048, 512, 512);
    mfma_gemm<MODE_VT><<<dim3(32,8,1), blk, 0, stream>>>(
        enc_c, nullptr, 0L, wv_c, 0L, nullptr, nullptr, (void*)vtws, 2048, 512, 512);

    // scores + softmax -> attn fp32 (output 1)
    attn_scores<<<dim3(32,8,4), blk, 0, stream>>>(qws, kws, pos_c, W5, attn_f);

    // out = attn @ v (batched over 32 (b,h)); A staged from fp32 attn in d_out
    mfma_gemm<MODE_AV><<<dim3(8,1,32), blk, 0, stream>>>(
        nullptr, attn_f, (long)(512*512), vtws, (long)(64*512),
        nullptr, nullptr, (void*)aows, 512, 64, 512);

    // fc + residual(enc fp32) -> res12 fp32; LN1 -> ln1ws bf16 + ln1f fp32
    mfma_gemm<MODE_FC><<<dim3(32,8,1), blk, 0, stream>>>(
        aows, nullptr, 0L, wfc_c, 0L, nullptr, enc_f, (void*)res12, 2048, 512, 512);
    ln_kernel<<<dim3(2048), blk, 0, stream>>>(res12, ln1_g, ln1_b, ln1ws, ln1f);

    // FFN, 4 chunks of 512 rows (hchunk = 2 MB)
    for (int c = 0; c < 4; ++c) {
        const u16*   ln1c = ln1ws + (long)c * 512 * 512;
        const float* l1fc = ln1f  + (long)c * 512 * 512;
        float*       resc = res12 + (long)c * 512 * 512;
        mfma_gemm<MODE_FFN1><<<dim3(8,32,1), blk, 0, stream>>>(
            ln1c, nullptr, 0L, fw1_c, 0L, ffn_b1, nullptr, (void*)hchunk,
            512, 2048, 512);
        mfma_gemm<MODE_FFN2><<<dim3(8,8,1), blk, 0, stream>>>(
            hchunk, nullptr, 0L, fw2_c, 0L, ffn_b2, l1fc, (void*)resc,
            512, 512, 2048);
    }
    ln_kernel<<<dim3(2048), blk, 0, stream>>>(res12, ln2_g, ln2_b, nullptr, out0_f);
}

// Round 5
// 261.524 us; speedup vs baseline: 1.5797x; 1.5797x over previous
//
#include <hip/hip_runtime.h>
#include <hip/hip_bf16.h>

typedef unsigned short u16;
typedef unsigned int u32;
typedef __attribute__((ext_vector_type(8))) short short8;
typedef __attribute__((ext_vector_type(4))) short short4v;
typedef __attribute__((ext_vector_type(4))) float floatx4;

__device__ __forceinline__ float bf2f(u16 u) {
    union { u32 u; float f; } x; x.u = ((u32)u) << 16; return x.f;
}
__device__ __forceinline__ u16 f2bf(float f) {
    union { float f; u32 u; } x; x.f = f;
    u32 r = x.u + 0x7FFFu + ((x.u >> 16) & 1u);
    return (u16)(r >> 16);
}

// ---------------------------------------------------------------------------
// fp32 -> bf16 canonicalization of the 8 big tensors (float4 granular)
// ---------------------------------------------------------------------------
struct Cvt8 {
    const float* src[8];
    u16* dst[8];
    int pre[9];
};

__global__ __launch_bounds__(256) void convert8(Cvt8 a) {
    int total = a.pre[8];
    for (int g = blockIdx.x * 256 + threadIdx.x; g < total; g += gridDim.x * 256) {
        int seg = 0;
        while (a.pre[seg + 1] <= g) seg++;
        int off = g - a.pre[seg];
        float4 f = ((const float4*)a.src[seg])[off];
        short4v o;
        o[0] = (short)f2bf(f.x); o[1] = (short)f2bf(f.y);
        o[2] = (short)f2bf(f.z); o[3] = (short)f2bf(f.w);
        *(short4v*)(a.dst[seg] + (long)off * 4) = o;
    }
}

// ---------------------------------------------------------------------------
// Fold affine rel-pos MLP: W5[d][0..3]=Weff, W5[d][4]=beff  (fp32, [64][8])
// ---------------------------------------------------------------------------
__global__ void prep_w5(const float* __restrict__ w1, const float* __restrict__ b1,
                        const float* __restrict__ w2, const float* __restrict__ b2,
                        float* __restrict__ W5) {
    int d = threadIdx.x;  // 64 threads
    float a0=0.f,a1=0.f,a2=0.f,a3=0.f,ab=0.f;
    for (int e=0;e<64;++e) {
        float w = w2[d*64+e];
        a0 = fmaf(w, w1[e*4+0], a0);
        a1 = fmaf(w, w1[e*4+1], a1);
        a2 = fmaf(w, w1[e*4+2], a2);
        a3 = fmaf(w, w1[e*4+3], a3);
        ab = fmaf(w, b1[e], ab);
    }
    W5[d*8+0]=a0; W5[d*8+1]=a1; W5[d*8+2]=a2; W5[d*8+3]=a3;
    W5[d*8+4]=ab + b2[d];
    W5[d*8+5]=0.f; W5[d*8+6]=0.f; W5[d*8+7]=0.f;
}

// ---------------------------------------------------------------------------
// MFMA bf16 GEMM, 64x64 tile, BK=64 (8 MFMA between barrier pairs).
// C[m,n] = sum_k A[m,k]*B[n,k]. MODE_AV stages A from fp32.
// ---------------------------------------------------------------------------
enum { MODE_QK=0, MODE_VT=1, MODE_AV=2, MODE_FC=3, MODE_FFN1=4, MODE_FFN2=5 };

template<int MODE>
__global__ __launch_bounds__(256,2)
void mfma_gemm(const u16* __restrict__ A, const float* __restrict__ Af, long sA,
               const u16* __restrict__ B, long sB,
               const float* __restrict__ biasf,
               const float* __restrict__ resf,
               const u16* __restrict__ resb,
               void* __restrict__ outp,
               int M, int N, int K)
{
    int bz = blockIdx.z;
    int m0 = blockIdx.x * 64, n0 = blockIdx.y * 64;
    __shared__ __align__(16) u16 As[64*72];   // 64 K-elems/row, pad 8
    __shared__ __align__(16) u16 Bs[64*72];
    int tid = threadIdx.x;
    int lane = tid & 63, wave = tid >> 6;
    int wm = (wave >> 1) * 32, wn = (wave & 1) * 32;
    int mrow = lane & 15, quad = lane >> 4;
    floatx4 zz = {0.f,0.f,0.f,0.f};
    floatx4 acc[2][2];
    acc[0][0]=zz; acc[0][1]=zz; acc[1][0]=zz; acc[1][1]=zz;
    int r = tid >> 3;          // 0..31 (stage rows r and r+32)
    int c8 = (tid & 7) * 8;    // 0..56
    const u16*   pa  = A  + (long)bz * sA + (long)(m0 + r) * K + c8;
    const float* paf = Af + (long)bz * sA + (long)(m0 + r) * K + c8;
    const u16*   pb  = B  + (long)bz * sB + (long)(n0 + r) * K + c8;
    u16* asp = &As[r*72 + c8];
    u16* bsp = &Bs[r*72 + c8];
    const u16* a0p = &As[(wm + mrow)*72];
    const u16* a1p = &As[(wm + 16 + mrow)*72];
    const u16* b0p = &Bs[(wn + mrow)*72];
    const u16* b1p = &Bs[(wn + 16 + mrow)*72];
    for (int k0 = 0; k0 < K; k0 += 64) {
        if constexpr (MODE == MODE_AV) {
            #pragma unroll
            for (int h=0; h<2; ++h) {
                const float* p = paf + k0 + (long)h*32*K;
                floatx4 f0 = *(const floatx4*)(p);
                floatx4 f1 = *(const floatx4*)(p + 4);
                short4v t0, t1;
                #pragma unroll
                for (int e=0;e<4;++e) { t0[e]=(short)f2bf(f0[e]); t1[e]=(short)f2bf(f1[e]); }
                *(short4v*)(asp + h*32*72)     = t0;
                *(short4v*)(asp + h*32*72 + 4) = t1;
            }
        } else {
            *(short8*)asp            = *(const short8*)(pa + k0);
            *(short8*)(asp + 32*72)  = *(const short8*)(pa + k0 + 32*K);
        }
        *(short8*)bsp            = *(const short8*)(pb + k0);
        *(short8*)(bsp + 32*72)  = *(const short8*)(pb + k0 + 32*K);
        __syncthreads();
        #pragma unroll
        for (int s=0; s<2; ++s) {
            int qo = s*32 + quad*8;
            short8 af0 = *(const short8*)(a0p + qo);
            short8 af1 = *(const short8*)(a1p + qo);
            short8 bf0 = *(const short8*)(b0p + qo);
            short8 bf1 = *(const short8*)(b1p + qo);
            acc[0][0] = __builtin_amdgcn_mfma_f32_16x16x32_bf16(af0, bf0, acc[0][0], 0,0,0);
            acc[0][1] = __builtin_amdgcn_mfma_f32_16x16x32_bf16(af0, bf1, acc[0][1], 0,0,0);
            acc[1][0] = __builtin_amdgcn_mfma_f32_16x16x32_bf16(af1, bf0, acc[1][0], 0,0,0);
            acc[1][1] = __builtin_amdgcn_mfma_f32_16x16x32_bf16(af1, bf1, acc[1][1], 0,0,0);
        }
        __syncthreads();
    }
    if constexpr (MODE == MODE_VT) {
        __shared__ __align__(16) float Cs[64][65];
        #pragma unroll
        for (int im=0; im<2; ++im)
        #pragma unroll
        for (int in=0; in<2; ++in)
        #pragma unroll
        for (int rr=0; rr<4; ++rr)
            Cs[wm + im*16 + quad*4 + rr][wn + in*16 + mrow] = acc[im][in][rr];
        __syncthreads();
        u16* vt = (u16*)outp;
        int b = m0 >> 9, i0b = m0 & 511, hh = n0 >> 6;
        #pragma unroll
        for (int t=0;t<16;++t) {
            int flat = tid + t*256;
            int d = flat >> 6, il = flat & 63;
            vt[(((long)(b*8 + hh)*64 + d) << 9) + i0b + il] = f2bf(Cs[il][d]);
        }
    } else {
        #pragma unroll
        for (int im=0; im<2; ++im)
        #pragma unroll
        for (int in=0; in<2; ++in)
        #pragma unroll
        for (int rr=0; rr<4; ++rr) {
            int mm = m0 + wm + im*16 + quad*4 + rr;
            int nn = n0 + wn + in*16 + mrow;
            float v = acc[im][in][rr];
            if constexpr (MODE == MODE_QK) {
                // merged Q+K: nn<512 -> q, else k (outp has k at +1048576 u16)
                int b = mm >> 9, i = mm & 511;
                int sel = nn >> 9, hh = (nn >> 6) & 7, d = nn & 63;
                ((u16*)outp)[(long)sel*1048576 + (((long)(b*8 + hh)*512 + i) << 6) + d] = f2bf(v);
            } else if constexpr (MODE == MODE_AV) {
                int b = bz >> 3, hh = bz & 7;
                ((u16*)outp)[((long)(b*512 + mm)) * 512 + hh*64 + nn] = f2bf(v);
            } else if constexpr (MODE == MODE_FC) {
                ((float*)outp)[(long)mm*512 + nn] = v + resf[(long)mm*512 + nn];
            } else if constexpr (MODE == MODE_FFN1) {
                float t = v + biasf[nn];
                ((u16*)outp)[(long)mm*2048 + nn] = f2bf(t > 0.f ? t : 0.f);
            } else { // MODE_FFN2
                ((float*)outp)[(long)mm*512 + nn] =
                    v + biasf[nn] + bf2f(resb[(long)mm*512 + nn]);
            }
        }
    }
}

// ---------------------------------------------------------------------------
// MFMA attention scores + softmax.
// s[j,i] = (1/8)[ sum_p pos[j,i,p]*G_p[j,i] + G_4[j,i] ],
// G_p[j,i] = sum_d (k[j,d]*W5[d][p]) * q[i,d]   (p=4 uses beff).
// Block = (16 j, bh). A-frags (5 scaled k-tiles) built in registers;
// B = plain q fragments loaded straight from global. S in LDS -> softmax.
// ---------------------------------------------------------------------------
__global__ __launch_bounds__(256,2)
void attn_scores(const u16* __restrict__ qws, const u16* __restrict__ kws,
                 const u16* __restrict__ pos, const float* __restrict__ W5g,
                 float* __restrict__ attn_of)
{
    int jt = blockIdx.x, h = blockIdx.y, b = blockIdx.z;
    int j0 = jt * 16;
    int bh = b*8 + h;
    const u16* qb = qws + (long)bh * 512 * 64;
    const u16* kb = kws + (long)bh * 512 * 64;
    __shared__ __align__(16) float W5s[512];
    __shared__ __align__(16) float S[16*516];    // stride 516: conflict-free
    __shared__ __align__(16) float redm[16][17];
    __shared__ __align__(16) float reds[16][17];
    __shared__ float rinvs[16];
    int tid = threadIdx.x;
    int lane = tid & 63, wave = tid >> 6;
    int m = lane & 15, quad = lane >> 4;
    if (tid < 64) {
        #pragma unroll
        for (int p=0;p<8;++p) W5s[tid*8+p] = W5g[tid*8+p];
    }
    __syncthreads();
    // build 5 scaled A-fragments (k-tile x W5 columns), 2 k-steps each
    short8 af[5][2];
    #pragma unroll
    for (int s=0; s<2; ++s) {
        short8 kf = *(const short8*)(kb + (long)(j0 + m)*64 + s*32 + quad*8);
        float kv[8];
        #pragma unroll
        for (int e=0;e<8;++e) kv[e] = bf2f((u16)kf[e]);
        int db = s*32 + quad*8;
        #pragma unroll
        for (int p=0;p<5;++p) {
            short8 t;
            #pragma unroll
            for (int e=0;e<8;++e) t[e] = (short)f2bf(kv[e] * W5s[(db+e)*8 + p]);
            af[p][s] = t;
        }
    }
    floatx4 zz = {0.f,0.f,0.f,0.f};
    // 8 i-tiles of 16 per wave
    for (int it = wave*8; it < wave*8 + 8; ++it) {
        int i0 = it * 16;
        short8 bf0 = *(const short8*)(qb + (long)(i0 + m)*64 + quad*8);
        short8 bf1 = *(const short8*)(qb + (long)(i0 + m)*64 + 32 + quad*8);
        floatx4 a0 = __builtin_amdgcn_mfma_f32_16x16x32_bf16(af[0][0], bf0, zz, 0,0,0);
        floatx4 a1 = __builtin_amdgcn_mfma_f32_16x16x32_bf16(af[1][0], bf0, zz, 0,0,0);
        floatx4 a2 = __builtin_amdgcn_mfma_f32_16x16x32_bf16(af[2][0], bf0, zz, 0,0,0);
        floatx4 a3 = __builtin_amdgcn_mfma_f32_16x16x32_bf16(af[3][0], bf0, zz, 0,0,0);
        floatx4 a4 = __builtin_amdgcn_mfma_f32_16x16x32_bf16(af[4][0], bf0, zz, 0,0,0);
        a0 = __builtin_amdgcn_mfma_f32_16x16x32_bf16(af[0][1], bf1, a0, 0,0,0);
        a1 = __builtin_amdgcn_mfma_f32_16x16x32_bf16(af[1][1], bf1, a1, 0,0,0);
        a2 = __builtin_amdgcn_mfma_f32_16x16x32_bf16(af[2][1], bf1, a2, 0,0,0);
        a3 = __builtin_amdgcn_mfma_f32_16x16x32_bf16(af[3][1], bf1, a3, 0,0,0);
        a4 = __builtin_amdgcn_mfma_f32_16x16x32_bf16(af[4][1], bf1, a4, 0,0,0);
        // combine with pos and stash into S. lane's C elems: col=i0+m, row=quad*4+r
        long pb0 = (((long)(b*512 + j0 + quad*4))*512 + i0 + m) * 4;
        #pragma unroll
        for (int rr=0; rr<4; ++rr) {
            uint2 pp = *(const uint2*)&pos[pb0 + (long)rr*2048];
            float p0 = bf2f((u16)(pp.x & 0xffff));
            float p1 = bf2f((u16)(pp.x >> 16));
            float p2 = bf2f((u16)(pp.y & 0xffff));
            float p3 = bf2f((u16)(pp.y >> 16));
            float sv = a4[rr];
            sv = fmaf(p0, a0[rr], sv);
            sv = fmaf(p1, a1[rr], sv);
            sv = fmaf(p2, a2[rr], sv);
            sv = fmaf(p3, a3[rr], sv);
            S[(quad*4 + rr)*516 + i0 + m] = sv * 0.125f;
        }
    }
    __syncthreads();
    // softmax over i (512) per j-row: 16 threads per row
    int j = tid >> 4, sub = tid & 15;
    float mx = -1e30f;
    for (int t=0;t<32;++t) mx = fmaxf(mx, S[j*516 + sub + t*16]);
    redm[j][sub] = mx;
    __syncthreads();
    float mval = redm[j][0];
    #pragma unroll
    for (int p=1;p<16;++p) mval = fmaxf(mval, redm[j][p]);
    float sum = 0.f;
    for (int t=0;t<32;++t) {
        int i = sub + t*16;
        float e = __expf(S[j*516 + i] - mval);
        S[j*516 + i] = e;
        sum += e;
    }
    reds[j][sub] = sum;
    __syncthreads();
    float tot = 0.f;
    #pragma unroll
    for (int p=0;p<16;++p) tot += reds[j][p];
    if (sub == 0) rinvs[j] = 1.0f / tot;
    __syncthreads();
    long rowbase = ((long)bh * 512 + j0) * 512;
    for (int t=0;t<16;++t) {
        int idx = (tid + t*256) * 2;
        int jj = idx >> 9, i = idx & 511;
        float ri = rinvs[jj];
        float2 f2; f2.x = S[jj*516 + i]*ri; f2.y = S[jj*516 + i + 1]*ri;
        *(float2*)&attn_of[rowbase + (long)jj*512 + i] = f2;
    }
}

// ---------------------------------------------------------------------------
// LayerNorm over 512 cols, fp32 in; bf16 (outb) and/or fp32 (outf) out.
// In-place (x == outf) is safe: all reads precede writes per row-block.
// ---------------------------------------------------------------------------
__global__ __launch_bounds__(256)
void ln_kernel(const float* __restrict__ x, const float* __restrict__ g,
               const float* __restrict__ bb, u16* __restrict__ outb,
               float* __restrict__ outf)
{
    int row = blockIdx.x, tid = threadIdx.x;
    const float* xr = x + (long)row * 512;
    float v0 = xr[tid*2], v1 = xr[tid*2+1];
    __shared__ float r1[256], r2[256];
    r1[tid] = v0 + v1;
    r2[tid] = v0*v0 + v1*v1;
    __syncthreads();
    for (int sft=128; sft>0; sft>>=1) {
        if (tid < sft) { r1[tid] += r1[tid+sft]; r2[tid] += r2[tid+sft]; }
        __syncthreads();
    }
    float mu = r1[0] * (1.0f/512.0f);
    float var = r2[0] * (1.0f/512.0f) - mu*mu;
    float rs = rsqrtf(var + 1e-6f);
    float y0 = fmaf((v0-mu)*rs, g[tid*2],   bb[tid*2]);
    float y1 = fmaf((v1-mu)*rs, g[tid*2+1], bb[tid*2+1]);
    if (outf) {
        float2 f2; f2.x = y0; f2.y = y1;
        *(float2*)&outf[(long)row*512 + tid*2] = f2;
    }
    if (outb) {
        ((u32*)outb)[row*256 + tid] = (u32)f2bf(y0) | ((u32)f2bf(y1) << 16);
    }
}

// ---------------------------------------------------------------------------
// ws layout (MB), peak 22.0 + 4KB (proven safe at 22.13):
//   0-2    enc_c bf16            [dead after projections]
//   2-10   pos_c bf16            -> hws [2048,2048] bf16 (8MB) after attn
//   10-10.5 wq_c; 10.5-11 wk_c (contiguous => merged QK GEMM)
//   11-11.5 wv_c; 11.5-12 wfc_c
//   12-14  fw1_c; 14-16 fw2_c
//   16-18  qws  -> aows (after attn)
//   18-20  kws  -> ln1ws bf16 (after attn)
//   20-22  vtws [dead after AV]
//   22+    W5 (2KB)
// res1/res2 (fp32 4MB) live in d_out's output-0 slab (in-place LN).
// ---------------------------------------------------------------------------
extern "C" void kernel_launch(void* const* d_in, const int* in_sizes, int n_in,
                              void* d_out, int out_size, void* d_ws, size_t ws_size,
                              hipStream_t stream)
{
    const float* enc_f  = (const float*)d_in[0];
    const float* rp_w1  = (const float*)d_in[6];
    const float* rp_b1  = (const float*)d_in[7];
    const float* rp_w2  = (const float*)d_in[8];
    const float* rp_b2  = (const float*)d_in[9];
    const float* ln1_g  = (const float*)d_in[10];
    const float* ln1_b  = (const float*)d_in[11];
    const float* ln2_g  = (const float*)d_in[12];
    const float* ln2_b  = (const float*)d_in[13];
    const float* ffn_b1 = (const float*)d_in[15];
    const float* ffn_b2 = (const float*)d_in[17];

    char* ws = (char*)d_ws;
    const size_t MB = 1048576ul;
    u16* enc_c = (u16*)(ws + 0);
    u16* pos_c = (u16*)(ws + 2*MB);
    u16* wq_c  = (u16*)(ws + 10*MB);
    u16* wv_c  = (u16*)(ws + 11*MB);
    u16* wfc_c = (u16*)(ws + 11*MB + 524288);
    u16* fw1_c = (u16*)(ws + 12*MB);
    u16* fw2_c = (u16*)(ws + 14*MB);
    u16* qws   = (u16*)(ws + 16*MB);          // kws contiguous at +2MB
    u16* kws   = (u16*)(ws + 18*MB);
    u16* vtws  = (u16*)(ws + 20*MB);
    u16* hws   = (u16*)(ws + 2*MB);           // alias pos_c (dead after attn)
    u16* aows  = (u16*)(ws + 16*MB);          // alias qws  (dead after attn)
    u16* ln1ws = (u16*)(ws + 18*MB);          // alias kws  (dead after attn)
    float* W5  = (float*)(ws + 22*MB);

    float* out0_f = (float*)d_out;            // output 0: [4,512,512] fp32
    float* attn_f = out0_f + 1048576;         // output 1: [4,8,512,512] fp32
    float* res    = out0_f;                   // res1/res2 live here (in-place)

    dim3 blk(256);

    Cvt8 ca;
    const float* srcs[8] = { enc_f, (const float*)d_in[1], (const float*)d_in[2],
                             (const float*)d_in[3], (const float*)d_in[4],
                             (const float*)d_in[5], (const float*)d_in[14],
                             (const float*)d_in[16] };
    u16* dsts[8] = { enc_c, pos_c, wq_c, (u16*)(ws + 10*MB + 524288), wv_c,
                     wfc_c, fw1_c, fw2_c };
    int sizes4[8] = { 262144, 1048576, 65536, 65536, 65536, 65536, 262144, 262144 };
    int pre = 0;
    for (int i = 0; i < 8; ++i) {
        ca.src[i] = srcs[i]; ca.dst[i] = dsts[i]; ca.pre[i] = pre;
        pre += sizes4[i];
    }
    ca.pre[8] = pre;
    convert8<<<dim3(8192), blk, 0, stream>>>(ca);

    prep_w5<<<dim3(1), dim3(64), 0, stream>>>(rp_w1, rp_b1, rp_w2, rp_b2, W5);

    // merged Q+K projection: B = [wq_c; wk_c] (contiguous), N=1024
    mfma_gemm<MODE_QK><<<dim3(32,16,1), blk, 0, stream>>>(
        enc_c, nullptr, 0L, wq_c, 0L, nullptr, nullptr, nullptr,
        (void*)qws, 2048, 1024, 512);
    mfma_gemm<MODE_VT><<<dim3(32,8,1), blk, 0, stream>>>(
        enc_c, nullptr, 0L, wv_c, 0L, nullptr, nullptr, nullptr,
        (void*)vtws, 2048, 512, 512);

    // MFMA scores + softmax -> attn fp32 (output 1)
    attn_scores<<<dim3(32,8,4), blk, 0, stream>>>(qws, kws, pos_c, W5, attn_f);

    // out = attn @ v (batched over 32 (b,h)); A staged from fp32 attn
    mfma_gemm<MODE_AV><<<dim3(8,1,32), blk, 0, stream>>>(
        nullptr, attn_f, (long)(512*512), vtws, (long)(64*512),
        nullptr, nullptr, nullptr, (void*)aows, 512, 64, 512);

    // fc + residual(enc fp32) -> res (d_out slab); LN1 -> ln1ws bf16
    mfma_gemm<MODE_FC><<<dim3(32,8,1), blk, 0, stream>>>(
        aows, nullptr, 0L, wfc_c, 0L, nullptr, enc_f, nullptr,
        (void*)res, 2048, 512, 512);
    ln_kernel<<<dim3(2048), blk, 0, stream>>>(res, ln1_g, ln1_b, ln1ws, nullptr);

    // FFN, full-size dispatches (hws = 8MB in dead pos region)
    mfma_gemm<MODE_FFN1><<<dim3(32,32,1), blk, 0, stream>>>(
        ln1ws, nullptr, 0L, fw1_c, 0L, ffn_b1, nullptr, nullptr,
        (void*)hws, 2048, 2048, 512);
    mfma_gemm<MODE_FFN2><<<dim3(32,8,1), blk, 0, stream>>>(
        hws, nullptr, 0L, fw2_c, 0L, ffn_b2, nullptr, ln1ws,
        (void*)res, 2048, 512, 2048);

    // LN2 in-place on res -> output 0
    ln_kernel<<<dim3(2048), blk, 0, stream>>>(res, ln2_g, ln2_b, nullptr, out0_f);
}

// Round 6
// 205.310 us; speedup vs baseline: 2.0123x; 1.2738x over previous
//
#include <hip/hip_runtime.h>
#include <hip/hip_bf16.h>

typedef unsigned short u16;
typedef unsigned int u32;
typedef __attribute__((ext_vector_type(8))) short short8;
typedef __attribute__((ext_vector_type(4))) short short4v;
typedef __attribute__((ext_vector_type(4))) float floatx4;

__device__ __forceinline__ float bf2f(u16 u) {
    union { u32 u; float f; } x; x.u = ((u32)u) << 16; return x.f;
}
__device__ __forceinline__ u16 f2bf(float f) {
    union { float f; u32 u; } x; x.f = f;
    u32 r = x.u + 0x7FFFu + ((x.u >> 16) & 1u);
    return (u16)(r >> 16);
}

// ---------------------------------------------------------------------------
// fp32 -> bf16 canonicalization of the 8 big tensors (float4 granular)
// ---------------------------------------------------------------------------
struct Cvt8 {
    const float* src[8];
    u16* dst[8];
    int pre[9];
};

__global__ __launch_bounds__(256) void convert8(Cvt8 a) {
    int total = a.pre[8];
    for (int g = blockIdx.x * 256 + threadIdx.x; g < total; g += gridDim.x * 256) {
        int seg = 0;
        while (a.pre[seg + 1] <= g) seg++;
        int off = g - a.pre[seg];
        float4 f = ((const float4*)a.src[seg])[off];
        short4v o;
        o[0] = (short)f2bf(f.x); o[1] = (short)f2bf(f.y);
        o[2] = (short)f2bf(f.z); o[3] = (short)f2bf(f.w);
        *(short4v*)(a.dst[seg] + (long)off * 4) = o;
    }
}

// ---------------------------------------------------------------------------
// Fold affine rel-pos MLP: W5[d][0..3]=Weff, W5[d][4]=beff  (fp32, [64][8])
// ---------------------------------------------------------------------------
__global__ void prep_w5(const float* __restrict__ w1, const float* __restrict__ b1,
                        const float* __restrict__ w2, const float* __restrict__ b2,
                        float* __restrict__ W5) {
    int d = threadIdx.x;  // 64 threads
    float a0=0.f,a1=0.f,a2=0.f,a3=0.f,ab=0.f;
    for (int e=0;e<64;++e) {
        float w = w2[d*64+e];
        a0 = fmaf(w, w1[e*4+0], a0);
        a1 = fmaf(w, w1[e*4+1], a1);
        a2 = fmaf(w, w1[e*4+2], a2);
        a3 = fmaf(w, w1[e*4+3], a3);
        ab = fmaf(w, b1[e], ab);
    }
    W5[d*8+0]=a0; W5[d*8+1]=a1; W5[d*8+2]=a2; W5[d*8+3]=a3;
    W5[d*8+4]=ab + b2[d];
    W5[d*8+5]=0.f; W5[d*8+6]=0.f; W5[d*8+7]=0.f;
}

// ---------------------------------------------------------------------------
// MFMA bf16 GEMM, 64x64 tile, BK=64, register-prefetch double buffering.
// C[m,n] = sum_k A[m,k]*B[n,k].
// MODE_QKV: merged q/k/v projection (N=1536; n0>=1024 -> V^T epilogue).
// MODE_AV:  A staged from fp32; blockIdx.z = batch (b,h).
// MODE_FC / MODE_FFN2: blockIdx.z = K-split index (partial to outp/outp2).
// ---------------------------------------------------------------------------
enum { MODE_QKV=0, MODE_AV=2, MODE_FC=3, MODE_FFN1=4, MODE_FFN2=5 };

template<int MODE>
__global__ __launch_bounds__(256,2)
void mfma_gemm(const u16* __restrict__ A, const float* __restrict__ Af,
               long sA, int lda,
               const u16* __restrict__ B, int ldb,
               const float* __restrict__ biasf,
               const float* __restrict__ resf,
               const u16* __restrict__ resb,
               void* __restrict__ outp, void* __restrict__ outp2,
               int M, int N, int K)
{
    int bz = blockIdx.z;
    int m0 = blockIdx.x * 64, n0 = blockIdx.y * 64;
    __shared__ __align__(16) u16 As[64*72];   // row stride 72 (pad 8)
    __shared__ __align__(16) u16 Bs[64*72];
    int tid = threadIdx.x;
    int lane = tid & 63, wave = tid >> 6;
    int wm = (wave >> 1) * 32, wn = (wave & 1) * 32;
    int mrow = lane & 15, quad = lane >> 4;
    floatx4 zz = {0.f,0.f,0.f,0.f};
    floatx4 acc[2][2];
    acc[0][0]=zz; acc[0][1]=zz; acc[1][0]=zz; acc[1][1]=zz;
    int r = tid >> 3;          // 0..31 (stage rows r, r+32)
    int c8 = (tid & 7) * 8;    // 0..56

    long abase = 0, bbase = 0;
    int koff = 0;
    if constexpr (MODE == MODE_AV) {
        abase = (long)bz * sA;
        bbase = (long)bz * (64L * 512L);
    }
    if constexpr (MODE == MODE_FC || MODE == MODE_FFN2) {
        koff = bz * K;
    }

    const u16*   pa  = A  + abase + (long)(m0 + r) * lda + koff + c8;
    const float* paf = Af + abase + (long)(m0 + r) * lda + koff + c8;
    const u16*   pb  = B  + bbase + (long)(n0 + r) * ldb + koff + c8;
    u16* asp = &As[r*72 + c8];
    u16* bsp = &Bs[r*72 + c8];
    const u16* a0p = &As[(wm + mrow)*72];
    const u16* a1p = &As[(wm + 16 + mrow)*72];
    const u16* b0p = &Bs[(wn + mrow)*72];
    const u16* b1p = &Bs[(wn + 16 + mrow)*72];

    short8 ra0, ra1, rb0, rb1;
    floatx4 fa0, fa1, fa2, fa3;
    // prefetch tile k0=0
    if constexpr (MODE == MODE_AV) {
        fa0 = *(const floatx4*)(paf);
        fa1 = *(const floatx4*)(paf + 4);
        fa2 = *(const floatx4*)(paf + 32*lda);
        fa3 = *(const floatx4*)(paf + 32*lda + 4);
    } else {
        ra0 = *(const short8*)(pa);
        ra1 = *(const short8*)(pa + 32*lda);
    }
    rb0 = *(const short8*)(pb);
    rb1 = *(const short8*)(pb + 32*ldb);

    for (int k0 = 0; k0 < K; k0 += 64) {
        // stage current tile to LDS
        if constexpr (MODE == MODE_AV) {
            short4v t0,t1,t2,t3;
            #pragma unroll
            for (int e=0;e<4;++e) {
                t0[e]=(short)f2bf(fa0[e]); t1[e]=(short)f2bf(fa1[e]);
                t2[e]=(short)f2bf(fa2[e]); t3[e]=(short)f2bf(fa3[e]);
            }
            *(short4v*)asp           = t0;
            *(short4v*)(asp+4)       = t1;
            *(short4v*)(asp+32*72)   = t2;
            *(short4v*)(asp+32*72+4) = t3;
        } else {
            *(short8*)asp           = ra0;
            *(short8*)(asp + 32*72) = ra1;
        }
        *(short8*)bsp           = rb0;
        *(short8*)(bsp + 32*72) = rb1;
        __syncthreads();
        // prefetch next tile (overlaps ds_read + MFMA below)
        if (k0 + 64 < K) {
            int kn = k0 + 64;
            if constexpr (MODE == MODE_AV) {
                fa0 = *(const floatx4*)(paf + kn);
                fa1 = *(const floatx4*)(paf + kn + 4);
                fa2 = *(const floatx4*)(paf + kn + 32*lda);
                fa3 = *(const floatx4*)(paf + kn + 32*lda + 4);
            } else {
                ra0 = *(const short8*)(pa + kn);
                ra1 = *(const short8*)(pa + kn + 32*lda);
            }
            rb0 = *(const short8*)(pb + kn);
            rb1 = *(const short8*)(pb + kn + 32*ldb);
        }
        #pragma unroll
        for (int s=0; s<2; ++s) {
            int qo = s*32 + quad*8;
            short8 af0 = *(const short8*)(a0p + qo);
            short8 af1 = *(const short8*)(a1p + qo);
            short8 bf0 = *(const short8*)(b0p + qo);
            short8 bf1 = *(const short8*)(b1p + qo);
            acc[0][0] = __builtin_amdgcn_mfma_f32_16x16x32_bf16(af0, bf0, acc[0][0], 0,0,0);
            acc[0][1] = __builtin_amdgcn_mfma_f32_16x16x32_bf16(af0, bf1, acc[0][1], 0,0,0);
            acc[1][0] = __builtin_amdgcn_mfma_f32_16x16x32_bf16(af1, bf0, acc[1][0], 0,0,0);
            acc[1][1] = __builtin_amdgcn_mfma_f32_16x16x32_bf16(af1, bf1, acc[1][1], 0,0,0);
        }
        __syncthreads();
    }

    if constexpr (MODE == MODE_QKV) {
        if (n0 >= 1024) {
            // V^T epilogue: vt[(b,h)][d][i] via LDS transpose
            __shared__ __align__(16) float Cs[64][65];
            #pragma unroll
            for (int im=0; im<2; ++im)
            #pragma unroll
            for (int in=0; in<2; ++in)
            #pragma unroll
            for (int rr=0; rr<4; ++rr)
                Cs[wm + im*16 + quad*4 + rr][wn + in*16 + mrow] = acc[im][in][rr];
            __syncthreads();
            u16* vt = (u16*)outp2;
            int b = m0 >> 9, i0b = m0 & 511, hh = (n0 - 1024) >> 6;
            #pragma unroll
            for (int t=0;t<16;++t) {
                int flat = tid + t*256;
                int d = flat >> 6, il = flat & 63;
                vt[(((long)(b*8 + hh)*64 + d) << 9) + i0b + il] = f2bf(Cs[il][d]);
            }
        } else {
            #pragma unroll
            for (int im=0; im<2; ++im)
            #pragma unroll
            for (int in=0; in<2; ++in)
            #pragma unroll
            for (int rr=0; rr<4; ++rr) {
                int mm = m0 + wm + im*16 + quad*4 + rr;
                int nn = n0 + wn + in*16 + mrow;
                int b = mm >> 9, i = mm & 511;
                int sel = nn >> 9, hh = (nn >> 6) & 7, d = nn & 63;
                ((u16*)outp)[(long)sel*1048576 +
                             (((long)(b*8 + hh)*512 + i) << 6) + d]
                    = f2bf(acc[im][in][rr]);
            }
        }
    } else {
        #pragma unroll
        for (int im=0; im<2; ++im)
        #pragma unroll
        for (int in=0; in<2; ++in)
        #pragma unroll
        for (int rr=0; rr<4; ++rr) {
            int mm = m0 + wm + im*16 + quad*4 + rr;
            int nn = n0 + wn + in*16 + mrow;
            float v = acc[im][in][rr];
            if constexpr (MODE == MODE_AV) {
                int b = bz >> 3, hh = bz & 7;
                ((u16*)outp)[((long)(b*512 + mm)) * 512 + hh*64 + nn] = f2bf(v);
            } else if constexpr (MODE == MODE_FC) {
                float* OP = (float*)(bz ? outp2 : outp);
                OP[(long)mm*512 + nn] = bz ? v : v + resf[(long)mm*512 + nn];
            } else if constexpr (MODE == MODE_FFN1) {
                float t = v + biasf[nn];
                ((u16*)outp)[(long)mm*2048 + nn] = f2bf(t > 0.f ? t : 0.f);
            } else { // MODE_FFN2
                float* OP = (float*)(bz ? outp2 : outp);
                OP[(long)mm*512 + nn] =
                    bz ? v : v + biasf[nn] + bf2f(resb[(long)mm*512 + nn]);
            }
        }
    }
}

// ---------------------------------------------------------------------------
// MFMA attention scores + softmax (unchanged from round 5).
// s[j,i] = (1/8)[ sum_p pos[j,i,p]*G_p[j,i] + G_4[j,i] ],
// G_p[j,i] = sum_d (k[j,d]*W5[d][p]) * q[i,d].
// ---------------------------------------------------------------------------
__global__ __launch_bounds__(256,2)
void attn_scores(const u16* __restrict__ qws, const u16* __restrict__ kws,
                 const u16* __restrict__ pos, const float* __restrict__ W5g,
                 float* __restrict__ attn_of)
{
    int jt = blockIdx.x, h = blockIdx.y, b = blockIdx.z;
    int j0 = jt * 16;
    int bh = b*8 + h;
    const u16* qb = qws + (long)bh * 512 * 64;
    const u16* kb = kws + (long)bh * 512 * 64;
    __shared__ __align__(16) float W5s[512];
    __shared__ __align__(16) float S[16*516];
    __shared__ __align__(16) float redm[16][17];
    __shared__ __align__(16) float reds[16][17];
    __shared__ float rinvs[16];
    int tid = threadIdx.x;
    int lane = tid & 63, wave = tid >> 6;
    int m = lane & 15, quad = lane >> 4;
    if (tid < 64) {
        #pragma unroll
        for (int p=0;p<8;++p) W5s[tid*8+p] = W5g[tid*8+p];
    }
    __syncthreads();
    short8 af[5][2];
    #pragma unroll
    for (int s=0; s<2; ++s) {
        short8 kf = *(const short8*)(kb + (long)(j0 + m)*64 + s*32 + quad*8);
        float kv[8];
        #pragma unroll
        for (int e=0;e<8;++e) kv[e] = bf2f((u16)kf[e]);
        int db = s*32 + quad*8;
        #pragma unroll
        for (int p=0;p<5;++p) {
            short8 t;
            #pragma unroll
            for (int e=0;e<8;++e) t[e] = (short)f2bf(kv[e] * W5s[(db+e)*8 + p]);
            af[p][s] = t;
        }
    }
    floatx4 zz = {0.f,0.f,0.f,0.f};
    for (int it = wave*8; it < wave*8 + 8; ++it) {
        int i0 = it * 16;
        short8 bf0 = *(const short8*)(qb + (long)(i0 + m)*64 + quad*8);
        short8 bf1 = *(const short8*)(qb + (long)(i0 + m)*64 + 32 + quad*8);
        floatx4 a0 = __builtin_amdgcn_mfma_f32_16x16x32_bf16(af[0][0], bf0, zz, 0,0,0);
        floatx4 a1 = __builtin_amdgcn_mfma_f32_16x16x32_bf16(af[1][0], bf0, zz, 0,0,0);
        floatx4 a2 = __builtin_amdgcn_mfma_f32_16x16x32_bf16(af[2][0], bf0, zz, 0,0,0);
        floatx4 a3 = __builtin_amdgcn_mfma_f32_16x16x32_bf16(af[3][0], bf0, zz, 0,0,0);
        floatx4 a4 = __builtin_amdgcn_mfma_f32_16x16x32_bf16(af[4][0], bf0, zz, 0,0,0);
        a0 = __builtin_amdgcn_mfma_f32_16x16x32_bf16(af[0][1], bf1, a0, 0,0,0);
        a1 = __builtin_amdgcn_mfma_f32_16x16x32_bf16(af[1][1], bf1, a1, 0,0,0);
        a2 = __builtin_amdgcn_mfma_f32_16x16x32_bf16(af[2][1], bf1, a2, 0,0,0);
        a3 = __builtin_amdgcn_mfma_f32_16x16x32_bf16(af[3][1], bf1, a3, 0,0,0);
        a4 = __builtin_amdgcn_mfma_f32_16x16x32_bf16(af[4][1], bf1, a4, 0,0,0);
        long pb0 = (((long)(b*512 + j0 + quad*4))*512 + i0 + m) * 4;
        #pragma unroll
        for (int rr=0; rr<4; ++rr) {
            uint2 pp = *(const uint2*)&pos[pb0 + (long)rr*2048];
            float p0 = bf2f((u16)(pp.x & 0xffff));
            float p1 = bf2f((u16)(pp.x >> 16));
            float p2 = bf2f((u16)(pp.y & 0xffff));
            float p3 = bf2f((u16)(pp.y >> 16));
            float sv = a4[rr];
            sv = fmaf(p0, a0[rr], sv);
            sv = fmaf(p1, a1[rr], sv);
            sv = fmaf(p2, a2[rr], sv);
            sv = fmaf(p3, a3[rr], sv);
            S[(quad*4 + rr)*516 + i0 + m] = sv * 0.125f;
        }
    }
    __syncthreads();
    int j = tid >> 4, sub = tid & 15;
    float mx = -1e30f;
    for (int t=0;t<32;++t) mx = fmaxf(mx, S[j*516 + sub + t*16]);
    redm[j][sub] = mx;
    __syncthreads();
    float mval = redm[j][0];
    #pragma unroll
    for (int p=1;p<16;++p) mval = fmaxf(mval, redm[j][p]);
    float sum = 0.f;
    for (int t=0;t<32;++t) {
        int i = sub + t*16;
        float e = __expf(S[j*516 + i] - mval);
        S[j*516 + i] = e;
        sum += e;
    }
    reds[j][sub] = sum;
    __syncthreads();
    float tot = 0.f;
    #pragma unroll
    for (int p=0;p<16;++p) tot += reds[j][p];
    if (sub == 0) rinvs[j] = 1.0f / tot;
    __syncthreads();
    long rowbase = ((long)bh * 512 + j0) * 512;
    for (int t=0;t<16;++t) {
        int idx = (tid + t*256) * 2;
        int jj = idx >> 9, i = idx & 511;
        float ri = rinvs[jj];
        float2 f2; f2.x = S[jj*516 + i]*ri; f2.y = S[jj*516 + i + 1]*ri;
        *(float2*)&attn_of[rowbase + (long)jj*512 + i] = f2;
    }
}

// ---------------------------------------------------------------------------
// LayerNorm over 512 cols, fp32 in (x [+ x2 partial]); bf16/fp32 out.
// In-place (x == outf) safe: per-row reads precede writes.
// ---------------------------------------------------------------------------
__global__ __launch_bounds__(256)
void ln_kernel(const float* __restrict__ x, const float* __restrict__ x2,
               const float* __restrict__ g, const float* __restrict__ bb,
               u16* __restrict__ outb, float* __restrict__ outf)
{
    int row = blockIdx.x, tid = threadIdx.x;
    const float* xr = x + (long)row * 512;
    float v0 = xr[tid*2], v1 = xr[tid*2+1];
    if (x2) {
        const float* x2r = x2 + (long)row * 512;
        v0 += x2r[tid*2];
        v1 += x2r[tid*2+1];
    }
    __shared__ float r1[256], r2[256];
    r1[tid] = v0 + v1;
    r2[tid] = v0*v0 + v1*v1;
    __syncthreads();
    for (int sft=128; sft>0; sft>>=1) {
        if (tid < sft) { r1[tid] += r1[tid+sft]; r2[tid] += r2[tid+sft]; }
        __syncthreads();
    }
    float mu = r1[0] * (1.0f/512.0f);
    float var = r2[0] * (1.0f/512.0f) - mu*mu;
    float rs = rsqrtf(var + 1e-6f);
    float y0 = fmaf((v0-mu)*rs, g[tid*2],   bb[tid*2]);
    float y1 = fmaf((v1-mu)*rs, g[tid*2+1], bb[tid*2+1]);
    if (outf) {
        float2 f2; f2.x = y0; f2.y = y1;
        *(float2*)&outf[(long)row*512 + tid*2] = f2;
    }
    if (outb) {
        ((u32*)outb)[row*256 + tid] = (u32)f2bf(y0) | ((u32)f2bf(y1) << 16);
    }
}

// ---------------------------------------------------------------------------
// ws layout (MB), peak 22.0 + 4KB:
//   0-2     enc_c bf16          [dead after QKV]
//   2-10    pos_c bf16          -> p1_fc fp32 [2-6) after attn -> hws [2-10)
//   10-10.5 wq_c; 10.5-11 wk_c; 11-11.5 wv_c  (contiguous => merged QKV)
//   11.5-12 wfc_c; 12-14 fw1_c  -> [10-14) = p1_ffn2 fp32 after FFN1
//   14-16   fw2_c               [live till FFN2]
//   16-18   qws  -> aows
//   18-20   kws  -> ln1ws bf16
//   20-22   vtws                [dead after AV]
//   22+     W5 (2KB)
// res (4MB fp32) lives in d_out's output-0 slab (LN in-place).
// ---------------------------------------------------------------------------
extern "C" void kernel_launch(void* const* d_in, const int* in_sizes, int n_in,
                              void* d_out, int out_size, void* d_ws, size_t ws_size,
                              hipStream_t stream)
{
    const float* enc_f  = (const float*)d_in[0];
    const float* rp_w1  = (const float*)d_in[6];
    const float* rp_b1  = (const float*)d_in[7];
    const float* rp_w2  = (const float*)d_in[8];
    const float* rp_b2  = (const float*)d_in[9];
    const float* ln1_g  = (const float*)d_in[10];
    const float* ln1_b  = (const float*)d_in[11];
    const float* ln2_g  = (const float*)d_in[12];
    const float* ln2_b  = (const float*)d_in[13];
    const float* ffn_b1 = (const float*)d_in[15];
    const float* ffn_b2 = (const float*)d_in[17];

    char* ws = (char*)d_ws;
    const size_t MB = 1048576ul;
    u16* enc_c = (u16*)(ws + 0);
    u16* pos_c = (u16*)(ws + 2*MB);
    u16* wq_c  = (u16*)(ws + 10*MB);                // wk at +0.5MB, wv at +1MB
    u16* wk_c  = (u16*)(ws + 10*MB + 524288);
    u16* wv_c  = (u16*)(ws + 11*MB);
    u16* wfc_c = (u16*)(ws + 11*MB + 524288);
    u16* fw1_c = (u16*)(ws + 12*MB);
    u16* fw2_c = (u16*)(ws + 14*MB);
    u16* qws   = (u16*)(ws + 16*MB);                // kws contiguous at +2MB
    u16* vtws  = (u16*)(ws + 20*MB);
    u16* hws   = (u16*)(ws + 2*MB);                 // alias pos_c (dead)
    u16* aows  = (u16*)(ws + 16*MB);                // alias qws (dead)
    u16* ln1ws = (u16*)(ws + 18*MB);                // alias kws (dead)
    float* p1fc = (float*)(ws + 2*MB);              // FC partial 1 [2-6)
    float* p1f2 = (float*)(ws + 10*MB);             // FFN2 partial 1 [10-14)
    float* W5   = (float*)(ws + 22*MB);

    float* out0_f = (float*)d_out;                  // output 0 [4,512,512] fp32
    float* attn_f = out0_f + 1048576;               // output 1 [4,8,512,512] fp32
    float* res    = out0_f;                         // fp32 accum in-place

    dim3 blk(256);

    Cvt8 ca;
    const float* srcs[8] = { enc_f, (const float*)d_in[1], (const float*)d_in[2],
                             (const float*)d_in[3], (const float*)d_in[4],
                             (const float*)d_in[5], (const float*)d_in[14],
                             (const float*)d_in[16] };
    u16* dsts[8] = { enc_c, pos_c, wq_c, wk_c, wv_c, wfc_c, fw1_c, fw2_c };
    int sizes4[8] = { 262144, 1048576, 65536, 65536, 65536, 65536, 262144, 262144 };
    int pre = 0;
    for (int i = 0; i < 8; ++i) {
        ca.src[i] = srcs[i]; ca.dst[i] = dsts[i]; ca.pre[i] = pre;
        pre += sizes4[i];
    }
    ca.pre[8] = pre;
    convert8<<<dim3(8192), blk, 0, stream>>>(ca);

    prep_w5<<<dim3(1), dim3(64), 0, stream>>>(rp_w1, rp_b1, rp_w2, rp_b2, W5);

    // merged Q+K+V projection: B = [wq|wk|wv] (contiguous), N=1536
    mfma_gemm<MODE_QKV><<<dim3(32,24,1), blk, 0, stream>>>(
        enc_c, nullptr, 0L, 512, wq_c, 512, nullptr, nullptr, nullptr,
        (void*)qws, (void*)vtws, 2048, 1536, 512);

    // MFMA scores + softmax -> attn fp32 (output 1)
    attn_scores<<<dim3(32,8,4), blk, 0, stream>>>(qws, qws + 1048576, pos_c, W5, attn_f);

    // out = attn @ v (batched over 32 (b,h)); A staged from fp32 attn
    mfma_gemm<MODE_AV><<<dim3(8,1,32), blk, 0, stream>>>(
        nullptr, attn_f, 512L*512L, 512, vtws, 512, nullptr, nullptr, nullptr,
        (void*)aows, nullptr, 512, 64, 512);

    // fc + residual, split-K=2 (partials: res slab + p1fc); LN1 reduces
    mfma_gemm<MODE_FC><<<dim3(32,8,2), blk, 0, stream>>>(
        aows, nullptr, 0L, 512, wfc_c, 512, nullptr, enc_f, nullptr,
        (void*)res, (void*)p1fc, 2048, 512, 256);
    ln_kernel<<<dim3(2048), blk, 0, stream>>>(res, p1fc, ln1_g, ln1_b, ln1ws, nullptr);

    // FFN1 full (1024 blocks)
    mfma_gemm<MODE_FFN1><<<dim3(32,32,1), blk, 0, stream>>>(
        ln1ws, nullptr, 0L, 512, fw1_c, 512, ffn_b1, nullptr, nullptr,
        (void*)hws, nullptr, 2048, 2048, 512);

    // FFN2 split-K=2 (partials: res slab + p1f2); LN2 reduces -> output 0
    mfma_gemm<MODE_FFN2><<<dim3(32,8,2), blk, 0, stream>>>(
        hws, nullptr, 0L, 2048, fw2_c, 2048, ffn_b2, nullptr, ln1ws,
        (void*)res, (void*)p1f2, 2048, 512, 1024);
    ln_kernel<<<dim3(2048), blk, 0, stream>>>(res, p1f2, ln2_g, ln2_b, nullptr, out0_f);
}

// Round 7
// 198.500 us; speedup vs baseline: 2.0813x; 1.0343x over previous
//
#include <hip/hip_runtime.h>
#include <hip/hip_bf16.h>

typedef unsigned short u16;
typedef unsigned int u32;
typedef __attribute__((ext_vector_type(8))) short short8;
typedef __attribute__((ext_vector_type(4))) short short4v;
typedef __attribute__((ext_vector_type(4))) float floatx4;

__device__ __forceinline__ float bf2f(u16 u) {
    union { u32 u; float f; } x; x.u = ((u32)u) << 16; return x.f;
}
__device__ __forceinline__ u16 f2bf(float f) {
    union { float f; u32 u; } x; x.f = f;
    u32 r = x.u + 0x7FFFu + ((x.u >> 16) & 1u);
    return (u16)(r >> 16);
}

// ---------------------------------------------------------------------------
// fp32 -> bf16 canonicalization of the 8 big tensors (float4 granular)
// ---------------------------------------------------------------------------
struct Cvt8 {
    const float* src[8];
    u16* dst[8];
    int pre[9];
};

__global__ __launch_bounds__(256) void convert8(Cvt8 a) {
    int total = a.pre[8];
    for (int g = blockIdx.x * 256 + threadIdx.x; g < total; g += gridDim.x * 256) {
        int seg = 0;
        while (a.pre[seg + 1] <= g) seg++;
        int off = g - a.pre[seg];
        float4 f = ((const float4*)a.src[seg])[off];
        short4v o;
        o[0] = (short)f2bf(f.x); o[1] = (short)f2bf(f.y);
        o[2] = (short)f2bf(f.z); o[3] = (short)f2bf(f.w);
        *(short4v*)(a.dst[seg] + (long)off * 4) = o;
    }
}

// ---------------------------------------------------------------------------
// Fold affine rel-pos MLP: W5[d][0..3]=Weff, W5[d][4]=beff  (fp32, [64][8])
// ---------------------------------------------------------------------------
__global__ void prep_w5(const float* __restrict__ w1, const float* __restrict__ b1,
                        const float* __restrict__ w2, const float* __restrict__ b2,
                        float* __restrict__ W5) {
    int d = threadIdx.x;  // 64 threads
    float a0=0.f,a1=0.f,a2=0.f,a3=0.f,ab=0.f;
    for (int e=0;e<64;++e) {
        float w = w2[d*64+e];
        a0 = fmaf(w, w1[e*4+0], a0);
        a1 = fmaf(w, w1[e*4+1], a1);
        a2 = fmaf(w, w1[e*4+2], a2);
        a3 = fmaf(w, w1[e*4+3], a3);
        ab = fmaf(w, b1[e], ab);
    }
    W5[d*8+0]=a0; W5[d*8+1]=a1; W5[d*8+2]=a2; W5[d*8+3]=a3;
    W5[d*8+4]=ab + b2[d];
    W5[d*8+5]=0.f; W5[d*8+6]=0.f; W5[d*8+7]=0.f;
}

// ---------------------------------------------------------------------------
// 128x64-tile MFMA GEMM (BK=64, 16 MFMA/iter/wave, register prefetch).
// Wave grid 2x2: wm in {0,64}, wn in {0,32}; acc[4][2].
// MODE_QKV: N=1536 merged q/k/v (n0>=1024 -> V^T transpose epilogue).
// MODE_FFN1: bias + relu -> bf16.
// ---------------------------------------------------------------------------
enum { MODE_QKV=0, MODE_FFN1=1, MODE_FC=2, MODE_FFN2=3 };

template<int MODE>
__global__ __launch_bounds__(256,2)
void gemm128(const u16* __restrict__ A, int lda,
             const u16* __restrict__ B, int ldb,
             const float* __restrict__ biasf,
             void* __restrict__ outp, void* __restrict__ outp2,
             int K)
{
    int m0 = blockIdx.x * 128, n0 = blockIdx.y * 64;
    __shared__ __align__(16) u16 As[128*72];
    __shared__ __align__(16) u16 Bs[64*72];
    int tid = threadIdx.x;
    int lane = tid & 63, wave = tid >> 6;
    int wm = (wave >> 1) * 64, wn = (wave & 1) * 32;
    int mrow = lane & 15, quad = lane >> 4;
    floatx4 zz = {0.f,0.f,0.f,0.f};
    floatx4 acc[4][2];
    #pragma unroll
    for (int i=0;i<4;++i) { acc[i][0]=zz; acc[i][1]=zz; }

    int rA = tid >> 1, cA = (tid & 1) * 32;   // A: 128 rows, 2 thr/row
    int rB = tid >> 2, cB = (tid & 3) * 16;   // B: 64 rows, 4 thr/row
    const u16* pa = A + (long)(m0 + rA) * lda + cA;
    const u16* pb = B + (long)(n0 + rB) * ldb + cB;
    u16* asp = &As[rA*72 + cA];
    u16* bsp = &Bs[rB*72 + cB];

    short8 ra[4], rb[2];
    #pragma unroll
    for (int i=0;i<4;++i) ra[i] = *(const short8*)(pa + 8*i);
    #pragma unroll
    for (int i=0;i<2;++i) rb[i] = *(const short8*)(pb + 8*i);

    for (int k0 = 0; k0 < K; k0 += 64) {
        #pragma unroll
        for (int i=0;i<4;++i) *(short8*)(asp + 8*i) = ra[i];
        #pragma unroll
        for (int i=0;i<2;++i) *(short8*)(bsp + 8*i) = rb[i];
        __syncthreads();
        if (k0 + 64 < K) {
            int kn = k0 + 64;
            #pragma unroll
            for (int i=0;i<4;++i) ra[i] = *(const short8*)(pa + kn + 8*i);
            #pragma unroll
            for (int i=0;i<2;++i) rb[i] = *(const short8*)(pb + kn + 8*i);
        }
        #pragma unroll
        for (int s=0; s<2; ++s) {
            int qo = s*32 + quad*8;
            short8 bf0 = *(const short8*)(&Bs[(wn + mrow)*72 + qo]);
            short8 bf1 = *(const short8*)(&Bs[(wn + 16 + mrow)*72 + qo]);
            #pragma unroll
            for (int mt=0; mt<4; ++mt) {
                short8 af = *(const short8*)(&As[(wm + mt*16 + mrow)*72 + qo]);
                acc[mt][0] = __builtin_amdgcn_mfma_f32_16x16x32_bf16(af, bf0, acc[mt][0], 0,0,0);
                acc[mt][1] = __builtin_amdgcn_mfma_f32_16x16x32_bf16(af, bf1, acc[mt][1], 0,0,0);
            }
        }
        __syncthreads();
    }

    if constexpr (MODE == MODE_QKV) {
        if (n0 >= 1024) {
            // V^T epilogue: vt[(b,h)*64+d][i] via LDS transpose
            __shared__ __align__(16) float Cs[128][65];
            #pragma unroll
            for (int mt=0; mt<4; ++mt)
            #pragma unroll
            for (int nt=0; nt<2; ++nt)
            #pragma unroll
            for (int rr=0; rr<4; ++rr)
                Cs[wm + mt*16 + quad*4 + rr][wn + nt*16 + mrow] = acc[mt][nt][rr];
            __syncthreads();
            u16* vt = (u16*)outp2;
            int b = m0 >> 9, i0b = m0 & 511, hh = (n0 - 1024) >> 6;
            #pragma unroll
            for (int t=0;t<32;++t) {
                int flat = tid + t*256;
                int d = flat >> 7, il = flat & 127;
                vt[(((long)(b*8 + hh)*64 + d) << 9) + i0b + il] = f2bf(Cs[il][d]);
            }
        } else {
            #pragma unroll
            for (int mt=0; mt<4; ++mt)
            #pragma unroll
            for (int nt=0; nt<2; ++nt)
            #pragma unroll
            for (int rr=0; rr<4; ++rr) {
                int mm = m0 + wm + mt*16 + quad*4 + rr;
                int nn = n0 + wn + nt*16 + mrow;
                int b = mm >> 9, i = mm & 511;
                int sel = nn >> 9, hh = (nn >> 6) & 7, d = nn & 63;
                ((u16*)outp)[(long)sel*1048576 +
                             (((long)(b*8 + hh)*512 + i) << 6) + d]
                    = f2bf(acc[mt][nt][rr]);
            }
        }
    } else {  // MODE_FFN1
        #pragma unroll
        for (int mt=0; mt<4; ++mt)
        #pragma unroll
        for (int nt=0; nt<2; ++nt)
        #pragma unroll
        for (int rr=0; rr<4; ++rr) {
            int mm = m0 + wm + mt*16 + quad*4 + rr;
            int nn = n0 + wn + nt*16 + mrow;
            float t = acc[mt][nt][rr] + biasf[nn];
            ((u16*)outp)[(long)mm*2048 + nn] = f2bf(t > 0.f ? t : 0.f);
        }
    }
}

// ---------------------------------------------------------------------------
// 64x64-tile MFMA GEMM with split-K (blockIdx.z): MODE_FC / MODE_FFN2.
// bz==0 adds bias/residual; bz==1 writes raw partial to outp2.
// ---------------------------------------------------------------------------
template<int MODE>
__global__ __launch_bounds__(256,2)
void gemm64(const u16* __restrict__ A, int lda,
            const u16* __restrict__ B, int ldb,
            const float* __restrict__ biasf,
            const float* __restrict__ resf,
            const u16* __restrict__ resb,
            void* __restrict__ outp, void* __restrict__ outp2,
            int K)
{
    int bz = blockIdx.z;
    int m0 = blockIdx.x * 64, n0 = blockIdx.y * 64;
    __shared__ __align__(16) u16 As[64*72];
    __shared__ __align__(16) u16 Bs[64*72];
    int tid = threadIdx.x;
    int lane = tid & 63, wave = tid >> 6;
    int wm = (wave >> 1) * 32, wn = (wave & 1) * 32;
    int mrow = lane & 15, quad = lane >> 4;
    floatx4 zz = {0.f,0.f,0.f,0.f};
    floatx4 acc[2][2];
    acc[0][0]=zz; acc[0][1]=zz; acc[1][0]=zz; acc[1][1]=zz;
    int r = tid >> 3, c8 = (tid & 7) * 8;
    int koff = bz * K;
    const u16* pa = A + (long)(m0 + r) * lda + koff + c8;
    const u16* pb = B + (long)(n0 + r) * ldb + koff + c8;
    u16* asp = &As[r*72 + c8];
    u16* bsp = &Bs[r*72 + c8];
    const u16* a0p = &As[(wm + mrow)*72];
    const u16* a1p = &As[(wm + 16 + mrow)*72];
    const u16* b0p = &Bs[(wn + mrow)*72];
    const u16* b1p = &Bs[(wn + 16 + mrow)*72];
    short8 ra0 = *(const short8*)(pa);
    short8 ra1 = *(const short8*)(pa + 32*lda);
    short8 rb0 = *(const short8*)(pb);
    short8 rb1 = *(const short8*)(pb + 32*ldb);
    for (int k0 = 0; k0 < K; k0 += 64) {
        *(short8*)asp           = ra0;
        *(short8*)(asp + 32*72) = ra1;
        *(short8*)bsp           = rb0;
        *(short8*)(bsp + 32*72) = rb1;
        __syncthreads();
        if (k0 + 64 < K) {
            int kn = k0 + 64;
            ra0 = *(const short8*)(pa + kn);
            ra1 = *(const short8*)(pa + kn + 32*lda);
            rb0 = *(const short8*)(pb + kn);
            rb1 = *(const short8*)(pb + kn + 32*ldb);
        }
        #pragma unroll
        for (int s=0; s<2; ++s) {
            int qo = s*32 + quad*8;
            short8 af0 = *(const short8*)(a0p + qo);
            short8 af1 = *(const short8*)(a1p + qo);
            short8 bf0 = *(const short8*)(b0p + qo);
            short8 bf1 = *(const short8*)(b1p + qo);
            acc[0][0] = __builtin_amdgcn_mfma_f32_16x16x32_bf16(af0, bf0, acc[0][0], 0,0,0);
            acc[0][1] = __builtin_amdgcn_mfma_f32_16x16x32_bf16(af0, bf1, acc[0][1], 0,0,0);
            acc[1][0] = __builtin_amdgcn_mfma_f32_16x16x32_bf16(af1, bf0, acc[1][0], 0,0,0);
            acc[1][1] = __builtin_amdgcn_mfma_f32_16x16x32_bf16(af1, bf1, acc[1][1], 0,0,0);
        }
        __syncthreads();
    }
    #pragma unroll
    for (int im=0; im<2; ++im)
    #pragma unroll
    for (int in=0; in<2; ++in)
    #pragma unroll
    for (int rr=0; rr<4; ++rr) {
        int mm = m0 + wm + im*16 + quad*4 + rr;
        int nn = n0 + wn + in*16 + mrow;
        float v = acc[im][in][rr];
        float* OP = (float*)(bz ? outp2 : outp);
        if constexpr (MODE == MODE_FC) {
            OP[(long)mm*512 + nn] = bz ? v : v + resf[(long)mm*512 + nn];
        } else { // MODE_FFN2
            OP[(long)mm*512 + nn] =
                bz ? v : v + biasf[nn] + bf2f(resb[(long)mm*512 + nn]);
        }
    }
}

// ---------------------------------------------------------------------------
// MFMA attention scores + softmax + fused P@V.
// s[j,i] = (1/8)[ sum_p pos[j,i,p]*G_p[j,i] + G_4[j,i] ],
// G_p[j,i] = sum_d (k[j,d]*W5[d][p]) * q[i,d].
// After softmax: O[j,d] = sum_i P[j,i] * V[i,d] via vt[(bh)d][i] B-frags.
// ---------------------------------------------------------------------------
__global__ __launch_bounds__(256,2)
void attn_scores(const u16* __restrict__ qws, const u16* __restrict__ kws,
                 const u16* __restrict__ pos, const float* __restrict__ W5g,
                 const u16* __restrict__ vtws, u16* __restrict__ aows,
                 float* __restrict__ attn_of)
{
    int jt = blockIdx.x, h = blockIdx.y, b = blockIdx.z;
    int j0 = jt * 16;
    int bh = b*8 + h;
    const u16* qb = qws + (long)bh * 512 * 64;
    const u16* kb = kws + (long)bh * 512 * 64;
    __shared__ __align__(16) float W5s[512];
    __shared__ __align__(16) float S[16*516];
    __shared__ __align__(16) float redm[16][17];
    __shared__ __align__(16) float reds[16][17];
    __shared__ float rinvs[16];
    int tid = threadIdx.x;
    int lane = tid & 63, wave = tid >> 6;
    int m = lane & 15, quad = lane >> 4;
    if (tid < 64) {
        #pragma unroll
        for (int p=0;p<8;++p) W5s[tid*8+p] = W5g[tid*8+p];
    }
    __syncthreads();
    short8 af[5][2];
    #pragma unroll
    for (int s=0; s<2; ++s) {
        short8 kf = *(const short8*)(kb + (long)(j0 + m)*64 + s*32 + quad*8);
        float kv[8];
        #pragma unroll
        for (int e=0;e<8;++e) kv[e] = bf2f((u16)kf[e]);
        int db = s*32 + quad*8;
        #pragma unroll
        for (int p=0;p<5;++p) {
            short8 t;
            #pragma unroll
            for (int e=0;e<8;++e) t[e] = (short)f2bf(kv[e] * W5s[(db+e)*8 + p]);
            af[p][s] = t;
        }
    }
    floatx4 zz = {0.f,0.f,0.f,0.f};
    for (int it = wave*8; it < wave*8 + 8; ++it) {
        int i0 = it * 16;
        short8 bf0 = *(const short8*)(qb + (long)(i0 + m)*64 + quad*8);
        short8 bf1 = *(const short8*)(qb + (long)(i0 + m)*64 + 32 + quad*8);
        floatx4 a0 = __builtin_amdgcn_mfma_f32_16x16x32_bf16(af[0][0], bf0, zz, 0,0,0);
        floatx4 a1 = __builtin_amdgcn_mfma_f32_16x16x32_bf16(af[1][0], bf0, zz, 0,0,0);
        floatx4 a2 = __builtin_amdgcn_mfma_f32_16x16x32_bf16(af[2][0], bf0, zz, 0,0,0);
        floatx4 a3 = __builtin_amdgcn_mfma_f32_16x16x32_bf16(af[3][0], bf0, zz, 0,0,0);
        floatx4 a4 = __builtin_amdgcn_mfma_f32_16x16x32_bf16(af[4][0], bf0, zz, 0,0,0);
        a0 = __builtin_amdgcn_mfma_f32_16x16x32_bf16(af[0][1], bf1, a0, 0,0,0);
        a1 = __builtin_amdgcn_mfma_f32_16x16x32_bf16(af[1][1], bf1, a1, 0,0,0);
        a2 = __builtin_amdgcn_mfma_f32_16x16x32_bf16(af[2][1], bf1, a2, 0,0,0);
        a3 = __builtin_amdgcn_mfma_f32_16x16x32_bf16(af[3][1], bf1, a3, 0,0,0);
        a4 = __builtin_amdgcn_mfma_f32_16x16x32_bf16(af[4][1], bf1, a4, 0,0,0);
        long pb0 = (((long)(b*512 + j0 + quad*4))*512 + i0 + m) * 4;
        #pragma unroll
        for (int rr=0; rr<4; ++rr) {
            uint2 pp = *(const uint2*)&pos[pb0 + (long)rr*2048];
            float p0 = bf2f((u16)(pp.x & 0xffff));
            float p1 = bf2f((u16)(pp.x >> 16));
            float p2 = bf2f((u16)(pp.y & 0xffff));
            float p3 = bf2f((u16)(pp.y >> 16));
            float sv = a4[rr];
            sv = fmaf(p0, a0[rr], sv);
            sv = fmaf(p1, a1[rr], sv);
            sv = fmaf(p2, a2[rr], sv);
            sv = fmaf(p3, a3[rr], sv);
            S[(quad*4 + rr)*516 + i0 + m] = sv * 0.125f;
        }
    }
    __syncthreads();
    // softmax over i (512) per j-row
    int j = tid >> 4, sub = tid & 15;
    float mx = -1e30f;
    for (int t=0;t<32;++t) mx = fmaxf(mx, S[j*516 + sub + t*16]);
    redm[j][sub] = mx;
    __syncthreads();
    float mval = redm[j][0];
    #pragma unroll
    for (int p=1;p<16;++p) mval = fmaxf(mval, redm[j][p]);
    float sum = 0.f;
    for (int t=0;t<32;++t) {
        int i = sub + t*16;
        float e = __expf(S[j*516 + i] - mval);
        S[j*516 + i] = e;
        sum += e;
    }
    reds[j][sub] = sum;
    __syncthreads();
    float tot = 0.f;
    #pragma unroll
    for (int p=0;p<16;++p) tot += reds[j][p];
    if (sub == 0) rinvs[j] = 1.0f / tot;
    __syncthreads();
    // write normalized attention (output 1, fp32)
    long rowbase = ((long)bh * 512 + j0) * 512;
    for (int t=0;t<16;++t) {
        int idx = (tid + t*256) * 2;
        int jj = idx >> 9, i = idx & 511;
        float ri = rinvs[jj];
        float2 f2; f2.x = S[jj*516 + i]*ri; f2.y = S[jj*516 + i + 1]*ri;
        *(float2*)&attn_of[rowbase + (long)jj*512 + i] = f2;
    }
    // fused P@V: each wave computes O[16 j][16 d], d-range = wave*16..+16
    float rim = rinvs[m];
    const u16* vb = vtws + (long)bh * 64 * 512 + (long)(wave*16 + m)*512;
    floatx4 oacc = zz;
    for (int kk = 0; kk < 16; ++kk) {
        short8 afr;
        #pragma unroll
        for (int e=0;e<8;++e)
            afr[e] = (short)f2bf(S[m*516 + kk*32 + quad*8 + e] * rim);
        short8 bfr = *(const short8*)(vb + kk*32 + quad*8);
        oacc = __builtin_amdgcn_mfma_f32_16x16x32_bf16(afr, bfr, oacc, 0,0,0);
    }
    int dd = wave*16 + m;
    #pragma unroll
    for (int rr=0; rr<4; ++rr) {
        int jj = quad*4 + rr;
        aows[((long)(b*512 + j0 + jj))*512 + h*64 + dd] = f2bf(oacc[rr]);
    }
}

// ---------------------------------------------------------------------------
// LayerNorm over 512 cols, fp32 in (x [+ x2 partial]); bf16/fp32 out.
// ---------------------------------------------------------------------------
__global__ __launch_bounds__(256)
void ln_kernel(const float* __restrict__ x, const float* __restrict__ x2,
               const float* __restrict__ g, const float* __restrict__ bb,
               u16* __restrict__ outb, float* __restrict__ outf)
{
    int row = blockIdx.x, tid = threadIdx.x;
    const float* xr = x + (long)row * 512;
    float v0 = xr[tid*2], v1 = xr[tid*2+1];
    if (x2) {
        const float* x2r = x2 + (long)row * 512;
        v0 += x2r[tid*2];
        v1 += x2r[tid*2+1];
    }
    __shared__ float r1[256], r2[256];
    r1[tid] = v0 + v1;
    r2[tid] = v0*v0 + v1*v1;
    __syncthreads();
    for (int sft=128; sft>0; sft>>=1) {
        if (tid < sft) { r1[tid] += r1[tid+sft]; r2[tid] += r2[tid+sft]; }
        __syncthreads();
    }
    float mu = r1[0] * (1.0f/512.0f);
    float var = r2[0] * (1.0f/512.0f) - mu*mu;
    float rs = rsqrtf(var + 1e-6f);
    float y0 = fmaf((v0-mu)*rs, g[tid*2],   bb[tid*2]);
    float y1 = fmaf((v1-mu)*rs, g[tid*2+1], bb[tid*2+1]);
    if (outf) {
        float2 f2; f2.x = y0; f2.y = y1;
        *(float2*)&outf[(long)row*512 + tid*2] = f2;
    }
    if (outb) {
        ((u32*)outb)[row*256 + tid] = (u32)f2bf(y0) | ((u32)f2bf(y1) << 16);
    }
}

// ---------------------------------------------------------------------------
// ws layout (MB), peak 22.0 + 4KB:
//   0-2     enc_c bf16       -> aows bf16 (attn epilogue) -> dead after FC
//   2-10    pos_c bf16       -> p1fc fp32 [2-6) -> hws [2-10) after LN1
//   10-10.5 wq_c; 10.5-11 wk_c; 11-11.5 wv_c; 11.5-12 wfc_c
//   12-14   fw1_c            -> [10-14) = p1f2 fp32 after FFN1
//   14-16   fw2_c
//   16-18   qws;  18-20 kws  -> ln1ws bf16 at 18 after attn
//   20-22   vtws             [live through attn (fused PV)]
//   22+     W5 (2KB)
// res (4MB fp32) lives in d_out's output-0 slab (LN in-place).
// ---------------------------------------------------------------------------
extern "C" void kernel_launch(void* const* d_in, const int* in_sizes, int n_in,
                              void* d_out, int out_size, void* d_ws, size_t ws_size,
                              hipStream_t stream)
{
    const float* enc_f  = (const float*)d_in[0];
    const float* rp_w1  = (const float*)d_in[6];
    const float* rp_b1  = (const float*)d_in[7];
    const float* rp_w2  = (const float*)d_in[8];
    const float* rp_b2  = (const float*)d_in[9];
    const float* ln1_g  = (const float*)d_in[10];
    const float* ln1_b  = (const float*)d_in[11];
    const float* ln2_g  = (const float*)d_in[12];
    const float* ln2_b  = (const float*)d_in[13];
    const float* ffn_b1 = (const float*)d_in[15];
    const float* ffn_b2 = (const float*)d_in[17];

    char* ws = (char*)d_ws;
    const size_t MB = 1048576ul;
    u16* enc_c = (u16*)(ws + 0);
    u16* pos_c = (u16*)(ws + 2*MB);
    u16* wq_c  = (u16*)(ws + 10*MB);
    u16* wk_c  = (u16*)(ws + 10*MB + 524288);
    u16* wv_c  = (u16*)(ws + 11*MB);
    u16* wfc_c = (u16*)(ws + 11*MB + 524288);
    u16* fw1_c = (u16*)(ws + 12*MB);
    u16* fw2_c = (u16*)(ws + 14*MB);
    u16* qws   = (u16*)(ws + 16*MB);
    u16* kws   = (u16*)(ws + 18*MB);
    u16* vtws  = (u16*)(ws + 20*MB);
    u16* aows  = (u16*)(ws + 0);          // alias enc_c (dead after QKV)
    u16* hws   = (u16*)(ws + 2*MB);       // alias pos_c (dead after attn)
    u16* ln1ws = (u16*)(ws + 18*MB);      // alias kws (dead after attn)
    float* p1fc = (float*)(ws + 2*MB);    // FC partial (pos_c dead)
    float* p1f2 = (float*)(ws + 10*MB);   // FFN2 partial (weights dead)
    float* W5   = (float*)(ws + 22*MB);

    float* out0_f = (float*)d_out;
    float* attn_f = out0_f + 1048576;
    float* res    = out0_f;

    dim3 blk(256);

    Cvt8 ca;
    const float* srcs[8] = { enc_f, (const float*)d_in[1], (const float*)d_in[2],
                             (const float*)d_in[3], (const float*)d_in[4],
                             (const float*)d_in[5], (const float*)d_in[14],
                             (const float*)d_in[16] };
    u16* dsts[8] = { enc_c, pos_c, wq_c, wk_c, wv_c, wfc_c, fw1_c, fw2_c };
    int sizes4[8] = { 262144, 1048576, 65536, 65536, 65536, 65536, 262144, 262144 };
    int pre = 0;
    for (int i = 0; i < 8; ++i) {
        ca.src[i] = srcs[i]; ca.dst[i] = dsts[i]; ca.pre[i] = pre;
        pre += sizes4[i];
    }
    ca.pre[8] = pre;
    convert8<<<dim3(8192), blk, 0, stream>>>(ca);

    prep_w5<<<dim3(1), dim3(64), 0, stream>>>(rp_w1, rp_b1, rp_w2, rp_b2, W5);

    // merged Q+K+V projection (128x64 tiles): M=2048, N=1536, K=512
    gemm128<MODE_QKV><<<dim3(16,24,1), blk, 0, stream>>>(
        enc_c, 512, wq_c, 512, nullptr, (void*)qws, (void*)vtws, 512);

    // scores + softmax + fused P@V -> attn (output 1) + aows
    attn_scores<<<dim3(32,8,4), blk, 0, stream>>>(
        qws, kws, pos_c, W5, vtws, aows, attn_f);

    // fc + residual, split-K=2; LN1 reduces partials
    gemm64<MODE_FC><<<dim3(32,8,2), blk, 0, stream>>>(
        aows, 512, wfc_c, 512, nullptr, enc_f, nullptr,
        (void*)res, (void*)p1fc, 256);
    ln_kernel<<<dim3(2048), blk, 0, stream>>>(res, p1fc, ln1_g, ln1_b, ln1ws, nullptr);

    // FFN1 (128x64 tiles): M=2048, N=2048, K=512
    gemm128<MODE_FFN1><<<dim3(16,32,1), blk, 0, stream>>>(
        ln1ws, 512, fw1_c, 512, ffn_b1, (void*)hws, nullptr, 512);

    // FFN2 split-K=2; LN2 reduces -> output 0
    gemm64<MODE_FFN2><<<dim3(32,8,2), blk, 0, stream>>>(
        hws, 2048, fw2_c, 2048, ffn_b2, nullptr, ln1ws,
        (void*)res, (void*)p1f2, 1024);
    ln_kernel<<<dim3(2048), blk, 0, stream>>>(res, p1f2, ln2_g, ln2_b, nullptr, out0_f);
}